// Round 16
// baseline (598.253 us; speedup 1.0000x reference)
//
#include <hip/hip_runtime.h>
#include <hip/hip_bf16.h>
#include <hip/hip_fp16.h>

// Problem constants (GATPair_38800734552870) — all float tensors are fp32.
constexpr int NN   = 100000;   // nodes
constexpr int EE   = 1600000;  // edges
constexpr int BB   = 8192;
constexpr int PAD  = 48;       // padded CSR stride
constexpr float NEG_SLOPE = 0.2f;

constexpr int GBM = 128;                 // rows per gemm block (layer-1)
constexpr int GB = (NN + GBM - 1) / GBM; // 782 gemm blocks per tower
constexpr int GBM2 = 64;                 // rows per fused att1+gemm2 block
constexpr int GB2 = (NN + GBM2 - 1) / GBM2; // 1563 per tower
constexpr int AB2 = NN / 8;              // 12500 att blocks per tower (8 nodes/block)

// two-phase coalesced CSR build (counting sort by 256-node bucket)
constexpr int BSPAN = 256;
constexpr int NB    = (NN + BSPAN - 1) / BSPAN;   // 391 buckets per side
constexpr int BCAP  = 5120;
constexpr int CHA   = 2048;
constexpr int NCH   = (EE + CHA - 1) / CHA;       // 782 chunks per side

typedef _Float16 f16x8 __attribute__((ext_vector_type(8)));
typedef _Float16 f16x4 __attribute__((ext_vector_type(4)));
typedef float    f32x4 __attribute__((ext_vector_type(4)));

__device__ __forceinline__ float4 ld4(const float* p) { return *(const float4*)p; }

// ---------------- MFMA GEMM body: h = x @ W (fp16 out) + fused scores ----------
// 32-wide K phases. fp16 split hi/lo: D = xh*wh + xh*wl + xl*wh (fp32 acc).
// W from precomputed per-phase images (hi|lo, transposed, swizzled, 16 KB/phase).
template <typename TIN, int K>
__device__ __forceinline__
void gemm_mfma_body(int bid, const TIN* __restrict__ x,
                    const __half* __restrict__ Wimg,
                    const float* __restrict__ a_src, const float* __restrict__ a_dst,
                    __half* __restrict__ h,
                    float* __restrict__ ssrc, float* __restrict__ sdst,
                    char* lds) {
    constexpr bool HAS_LO = sizeof(TIN) == 4;
    char* const xh = lds;
    char* const xl = HAS_LO ? (lds + 8192) : lds;
    char* const wh = lds + (HAS_LO ? 16384 : 8192);
    char* const wl = wh + 8192;

    const int tid = threadIdx.x;
    const int wid = tid >> 6;
    const int lane = tid & 63;
    const int l15 = lane & 15;
    const int lg = lane >> 4;
    const int row0 = bid * GBM;

    f32x4 acc[2][8];
    #pragma unroll
    for (int i = 0; i < 2; ++i)
        #pragma unroll
        for (int j = 0; j < 8; ++j) acc[i][j] = (f32x4)0.f;

    for (int kt = 0; kt < K; kt += 32) {
        __syncthreads();
        if constexpr (HAS_LO) {
            #pragma unroll
            for (int i = 0; i < 4; ++i) {
                int idx = tid + i * 256;
                int row = idx >> 3, c4 = idx & 7;
                int grow = row0 + row; if (grow >= NN) grow = NN - 1;
                float4 v = ld4(&x[(size_t)grow * K + kt + c4 * 4]);
                f16x4 hv, lv;
                float f0 = v.x; _Float16 h0 = (_Float16)f0; hv[0] = h0; lv[0] = (_Float16)(f0 - (float)h0);
                float f1 = v.y; _Float16 h1 = (_Float16)f1; hv[1] = h1; lv[1] = (_Float16)(f1 - (float)h1);
                float f2 = v.z; _Float16 h2 = (_Float16)f2; hv[2] = h2; lv[2] = (_Float16)(f2 - (float)h2);
                float f3 = v.w; _Float16 h3 = (_Float16)f3; hv[3] = h3; lv[3] = (_Float16)(f3 - (float)h3);
                int byt = row * 64 + ((c4 * 8) ^ ((row & 3) << 4));
                *(f16x4*)(xh + byt) = hv;
                *(f16x4*)(xl + byt) = lv;
            }
        } else {
            #pragma unroll
            for (int i = 0; i < 2; ++i) {
                int idx = tid + i * 256;
                int row = idx >> 2, c8 = idx & 3;
                int grow = row0 + row; if (grow >= NN) grow = NN - 1;
                uint4 v = *(const uint4*)&x[(size_t)grow * 64 + kt + c8 * 8];
                int byt = row * 64 + ((c8 * 16) ^ ((row & 3) << 4));
                *(uint4*)(xh + byt) = v;
            }
        }
        {
            const uint4* ws = (const uint4*)((const char*)Wimg + (size_t)(kt >> 5) * 16384);
            uint4* wd = (uint4*)wh;
            #pragma unroll
            for (int i = 0; i < 4; ++i) wd[tid + i * 256] = ws[tid + i * 256];
        }
        __syncthreads();

        const int koff = lg * 16;
        f16x8 ah[2], al[2];
        #pragma unroll
        for (int rt = 0; rt < 2; ++rt) {
            int row = wid * 32 + rt * 16 + l15;
            int byt = row * 64 + (koff ^ ((row & 3) << 4));
            ah[rt] = *(const f16x8*)(xh + byt);
            if constexpr (HAS_LO) al[rt] = *(const f16x8*)(xl + byt);
        }
        #pragma unroll
        for (int ct = 0; ct < 8; ++ct) {
            int col = ct * 16 + l15;
            int byt = col * 64 + (koff ^ ((col & 3) << 4));
            f16x8 bh = *(const f16x8*)(wh + byt);
            f16x8 bl = *(const f16x8*)(wl + byt);
            #pragma unroll
            for (int rt = 0; rt < 2; ++rt) {
                acc[rt][ct] = __builtin_amdgcn_mfma_f32_16x16x32_f16(ah[rt], bh, acc[rt][ct], 0, 0, 0);
                acc[rt][ct] = __builtin_amdgcn_mfma_f32_16x16x32_f16(ah[rt], bl, acc[rt][ct], 0, 0, 0);
                if constexpr (HAS_LO)
                    acc[rt][ct] = __builtin_amdgcn_mfma_f32_16x16x32_f16(al[rt], bh, acc[rt][ct], 0, 0, 0);
            }
        }
    }

    float sv[8], dv[8];
    #pragma unroll
    for (int ct = 0; ct < 8; ++ct) {
        sv[ct] = a_src[ct * 16 + l15];
        dv[ct] = a_dst[ct * 16 + l15];
    }
    #pragma unroll
    for (int rt = 0; rt < 2; ++rt) {
        #pragma unroll
        for (int r = 0; r < 4; ++r) {
            int row = row0 + wid * 32 + rt * 16 + lg * 4 + r;
            bool ok = row < NN;
            if (ok) {
                #pragma unroll
                for (int ct = 0; ct < 8; ++ct)
                    h[(size_t)row * 128 + ct * 16 + l15] = __float2half(acc[rt][ct][r]);
            }
            float ps0 = 0.f, pd0 = 0.f, ps1 = 0.f, pd1 = 0.f;
            #pragma unroll
            for (int ct = 0; ct < 4; ++ct) {
                ps0 = fmaf(acc[rt][ct][r], sv[ct], ps0);
                pd0 = fmaf(acc[rt][ct][r], dv[ct], pd0);
                ps1 = fmaf(acc[rt][ct + 4][r], sv[ct + 4], ps1);
                pd1 = fmaf(acc[rt][ct + 4][r], dv[ct + 4], pd1);
            }
            ps0 += __shfl_xor(ps0, 1); pd0 += __shfl_xor(pd0, 1);
            ps1 += __shfl_xor(ps1, 1); pd1 += __shfl_xor(pd1, 1);
            ps0 += __shfl_xor(ps0, 2); pd0 += __shfl_xor(pd0, 2);
            ps1 += __shfl_xor(ps1, 2); pd1 += __shfl_xor(pd1, 2);
            ps0 += __shfl_xor(ps0, 4); pd0 += __shfl_xor(pd0, 4);
            ps1 += __shfl_xor(ps1, 4); pd1 += __shfl_xor(pd1, 4);
            ps0 += __shfl_xor(ps0, 8); pd0 += __shfl_xor(pd0, 8);
            ps1 += __shfl_xor(ps1, 8); pd1 += __shfl_xor(pd1, 8);
            if (ok && l15 == 0) {
                ssrc[row * 2 + 0] = ps0;
                ssrc[row * 2 + 1] = ps1;
                sdst[row * 2 + 0] = pd0;
                sdst[row * 2 + 1] = pd1;
            }
        }
    }
}

// ---------------- phase A: bucket sort (+ appended W-image prep blocks) ---------
__global__ __launch_bounds__(256)
void k_bucket(const int* __restrict__ el, const int* __restrict__ er,
              int* __restrict__ buf, int* __restrict__ gcur,
              const float* __restrict__ w1l, const float* __restrict__ w1r,
              const float* __restrict__ w2l, const float* __restrict__ w2r,
              __half* __restrict__ wi1l, __half* __restrict__ wi1r,
              __half* __restrict__ wi2l, __half* __restrict__ wi2r) {
    const int blk0 = blockIdx.x;
    if (blk0 >= 2 * NCH) {
        const int id = blk0 - 2 * NCH;
        const float* W;
        __half* img;
        int kt;
        if (id < 8) {
            W = (id >> 2) ? w1r : w1l;
            img = ((id >> 2) ? wi1r : wi1l) + (size_t)(id & 3) * 8192;
            kt = (id & 3) * 32;
        } else {
            int jx = id - 8;
            W = (jx >> 1) ? w2r : w2l;
            img = ((jx >> 1) ? wi2r : wi2l) + (size_t)(jx & 1) * 8192;
            kt = (jx & 1) * 32;
        }
        _Float16* imgh = (_Float16*)img;
        _Float16* imgl = imgh + 4096;
        for (int i = threadIdx.x; i < 4096; i += 256) {
            int kk = i >> 7, col = i & 127;
            float f = W[(size_t)(kt + kk) * 128 + col];
            _Float16 hi = (_Float16)f;
            _Float16 lo = (_Float16)(f - (float)hi);
            int hidx = col * 32 + (kk ^ ((col & 3) << 3));
            imgh[hidx] = hi;
            imgl[hidx] = lo;
        }
        return;
    }

    __shared__ int   P1[CHA];
    __shared__ short bkof[CHA];
    __shared__ int hist[NB];
    __shared__ int st[NB];
    __shared__ int ofs[NB];
    __shared__ int base[NB];
    __shared__ int sc[512];

    const int blk = blk0;
    const bool right = blk >= NCH;
    const int* __restrict__ e = right ? er : el;
    const int sideoff = right ? NB : 0;
    const int cbase = (right ? blk - NCH : blk) * CHA;
    int cnum = EE - cbase; if (cnum > CHA) cnum = CHA;
    const int t = threadIdx.x;

    for (int i = t; i < NB; i += 256) hist[i] = 0;
    __syncthreads();
    for (int i = t; i < cnum; i += 256) {
        int d = e[EE + cbase + i];
        atomicAdd(&hist[d >> 8], 1);
    }
    __syncthreads();

    sc[t]       = (t < NB)       ? hist[t]       : 0;
    sc[t + 256] = (t + 256 < NB) ? hist[t + 256] : 0;
    __syncthreads();
    for (int off = 1; off < 512; off <<= 1) {
        int a0 = sc[t];
        int a1 = sc[t + 256];
        int b0 = (t >= off)       ? sc[t - off]       : 0;
        int b1 = (t + 256 >= off) ? sc[t + 256 - off] : 0;
        __syncthreads();
        sc[t] = a0 + b0;
        sc[t + 256] = a1 + b1;
        __syncthreads();
    }
    for (int i = t; i < NB; i += 256) {
        int s = sc[i] - hist[i];
        st[i] = s;
        ofs[i] = s;
    }
    __syncthreads();
    for (int i = t; i < cnum; i += 256) {
        int d = e[EE + cbase + i];
        int s = e[cbase + i];
        int bk = d >> 8;
        int pos = atomicAdd(&ofs[bk], 1);
        P1[pos] = (s << 8) | (d & 255);
        bkof[pos] = (short)bk;
    }
    __syncthreads();
    for (int i = t; i < NB; i += 256)
        base[i] = hist[i] ? atomicAdd(&gcur[sideoff + i], hist[i]) : 0;
    __syncthreads();
    for (int j = t; j < cnum; j += 256) {
        int bk = bkof[j];
        buf[(size_t)(sideoff + bk) * BCAP + base[bk] + (j - st[bk])] = P1[j];
    }
}

// ---------------- phase B body: per-bucket mini-CSR in LDS, coalesced writeout --
__device__ __forceinline__
void csr_body(int blk, const int* __restrict__ buf, const int* __restrict__ gcur,
              int* __restrict__ cntl, int* __restrict__ cntr,
              int* __restrict__ csrl, int* __restrict__ csrr, char* smem) {
    int* lcnt = (int*)smem;
    int* lcsr = (int*)(smem + 1024);

    const bool right = blk >= NB;
    const int bk = right ? blk - NB : blk;
    int* __restrict__ cnt = right ? cntr : cntl;
    int* __restrict__ csr = right ? csrr : csrl;
    const int* __restrict__ src = buf + (size_t)blk * BCAP;
    const int count = gcur[blk];
    const int lo = bk * BSPAN;
    int nn = NN - lo; if (nn > BSPAN) nn = BSPAN;
    const int t = threadIdx.x;

    for (int i = t; i < nn; i += 256) lcnt[i] = 0;
    __syncthreads();
    for (int i = t; i < count; i += 256) {
        int v = src[i];
        int ld = v & 255;
        int s  = (int)((unsigned)v >> 8);
        int slot = atomicAdd(&lcnt[ld], 1);
        lcsr[ld * PAD + slot] = s;
    }
    __syncthreads();
    const int tot4 = (nn * PAD) >> 2;
    int4* __restrict__ dst4 = (int4*)&csr[(size_t)lo * PAD];
    const int4* __restrict__ s4 = (const int4*)lcsr;
    for (int i = t; i < tot4; i += 256) dst4[i] = s4[i];
    for (int i = t; i < nn; i += 256) cnt[lo + i] = lcnt[i];
}

// ---------------- fused: CSR build || layer-1 GEMMs (independent work) ----------
__global__ __launch_bounds__(256)
void k_csr_gemm1(const int* __restrict__ buf, const int* __restrict__ gcur,
                 int* __restrict__ cnt_l, int* __restrict__ cnt_r,
                 int* __restrict__ csr_l, int* __restrict__ csr_r,
                 const float* __restrict__ x_l, const float* __restrict__ x_r,
                 const __half* __restrict__ wi1l, const float* __restrict__ as1l,
                 const float* __restrict__ ad1l,
                 const __half* __restrict__ wi1r, const float* __restrict__ as1r,
                 const float* __restrict__ ad1r,
                 __half* __restrict__ h_l, __half* __restrict__ h_r,
                 float* __restrict__ ssrc_l, float* __restrict__ sdst_l,
                 float* __restrict__ ssrc_r, float* __restrict__ sdst_r) {
    __shared__ __align__(16) char smem[50176];
    int b = blockIdx.x;
    if (b < 2 * NB) {
        csr_body(b, buf, gcur, cnt_l, cnt_r, csr_l, csr_r, smem);
    } else {
        b -= 2 * NB;
        if (b < GB)
            gemm_mfma_body<float, 128>(b, x_l, wi1l, as1l, ad1l,
                                       h_l, ssrc_l, sdst_l, smem);
        else
            gemm_mfma_body<float, 128>(b - GB, x_r, wi1r, as1r, ad1r,
                                       h_r, ssrc_r, sdst_r, smem);
    }
}

// ---------------- layer-2 GEMMs standalone (fallback path) ----------------------
__global__ __launch_bounds__(256)
void k_gemm2x(const __half* __restrict__ f_l, const __half* __restrict__ f_r,
              const __half* __restrict__ wi2l, const float* __restrict__ as2l,
              const float* __restrict__ ad2l,
              const __half* __restrict__ wi2r, const float* __restrict__ as2r,
              const float* __restrict__ ad2r,
              __half* __restrict__ h_l, __half* __restrict__ h_r,
              float* __restrict__ ssrc_l, float* __restrict__ sdst_l,
              float* __restrict__ ssrc_r, float* __restrict__ sdst_r) {
    __shared__ __align__(16) char smem[24576];
    int b = blockIdx.x;
    if (b < GB)
        gemm_mfma_body<__half, 64>(b, (const __half*)f_l, wi2l, as2l, ad2l,
                                   h_l, ssrc_l, sdst_l, smem);
    else
        gemm_mfma_body<__half, 64>(b - GB, (const __half*)f_r, wi2r, as2r, ad2r,
                                   h_r, ssrc_r, sdst_r, smem);
}

// ---------------- per-destination softmax aggregation (static shift m=0) --------
// Template WRITER: 0 = global feat store, 1 = LDS store (fused att1+gemm2).
template <int WRITER>
__device__ __forceinline__
void att_body_t(int n, int row_local, const __half* __restrict__ h,
                const float* __restrict__ ssrc, const float* __restrict__ sdst,
                const int* __restrict__ cnt, const int* __restrict__ csr,
                const float* __restrict__ bias, __half* __restrict__ out,
                char* featlds) {
    const int g  = threadIdx.x & 31;
    const int hs = g >> 4;
    const int j  = g & 15;
    const int ch = g * 4;

    float sd = sdst[n * 2 + hs];
    float es = ssrc[n * 2 + hs] + sd;
    es = es > 0.f ? es : NEG_SLOPE * es;
    const float wself = __expf(es);
    float zl = 0.f;

    uint2 sv = *(const uint2*)&h[(size_t)n * 128 + ch];
    __half2 sh0 = *(__half2*)&sv.x, sh1 = *(__half2*)&sv.y;
    float2 p01 = __half22float2(sh0), p23 = __half22float2(sh1);
    float a0 = wself * p01.x, a1 = wself * p01.y;
    float a2 = wself * p23.x, a3 = wself * p23.y;

    int b = n * PAD;
    const int e = b + cnt[n];
    while (b < e) {
        int c = e - b; if (c > 16) c = 16;
        int idx = b + (j < c ? j : c - 1);
        int sj = csr[idx];
        float ev = ssrc[sj * 2 + hs] + sd;
        ev = ev > 0.f ? ev : NEG_SLOPE * ev;
        float w = (j < c) ? __expf(ev) : 0.f;
        zl += w;
        int jj = 0;
        for (; jj + 4 <= c; jj += 4) {
            int s0 = __shfl(sj, jj,     32);
            int s1 = __shfl(sj, jj + 1, 32);
            int s2 = __shfl(sj, jj + 2, 32);
            int s3 = __shfl(sj, jj + 3, 32);
            float w0 = __shfl(w, hs * 16 + jj,     32);
            float w1 = __shfl(w, hs * 16 + jj + 1, 32);
            float w2 = __shfl(w, hs * 16 + jj + 2, 32);
            float w3 = __shfl(w, hs * 16 + jj + 3, 32);
            uint2 u0 = *(const uint2*)&h[(size_t)(unsigned)(s0 * 128 + ch)];
            uint2 u1 = *(const uint2*)&h[(size_t)(unsigned)(s1 * 128 + ch)];
            uint2 u2 = *(const uint2*)&h[(size_t)(unsigned)(s2 * 128 + ch)];
            uint2 u3 = *(const uint2*)&h[(size_t)(unsigned)(s3 * 128 + ch)];
            float2 f0a = __half22float2(*(__half2*)&u0.x), f0b = __half22float2(*(__half2*)&u0.y);
            float2 f1a = __half22float2(*(__half2*)&u1.x), f1b = __half22float2(*(__half2*)&u1.y);
            float2 f2a = __half22float2(*(__half2*)&u2.x), f2b = __half22float2(*(__half2*)&u2.y);
            float2 f3a = __half22float2(*(__half2*)&u3.x), f3b = __half22float2(*(__half2*)&u3.y);
            a0 = fmaf(w0, f0a.x, a0); a1 = fmaf(w0, f0a.y, a1);
            a2 = fmaf(w0, f0b.x, a2); a3 = fmaf(w0, f0b.y, a3);
            a0 = fmaf(w1, f1a.x, a0); a1 = fmaf(w1, f1a.y, a1);
            a2 = fmaf(w1, f1b.x, a2); a3 = fmaf(w1, f1b.y, a3);
            a0 = fmaf(w2, f2a.x, a0); a1 = fmaf(w2, f2a.y, a1);
            a2 = fmaf(w2, f2b.x, a2); a3 = fmaf(w2, f2b.y, a3);
            a0 = fmaf(w3, f3a.x, a0); a1 = fmaf(w3, f3a.y, a1);
            a2 = fmaf(w3, f3b.x, a2); a3 = fmaf(w3, f3b.y, a3);
        }
        for (; jj < c; ++jj) {
            int s0   = __shfl(sj, jj, 32);
            float w0 = __shfl(w, hs * 16 + jj, 32);
            uint2 u0 = *(const uint2*)&h[(size_t)(unsigned)(s0 * 128 + ch)];
            float2 f0a = __half22float2(*(__half2*)&u0.x), f0b = __half22float2(*(__half2*)&u0.y);
            a0 = fmaf(w0, f0a.x, a0); a1 = fmaf(w0, f0a.y, a1);
            a2 = fmaf(w0, f0b.x, a2); a3 = fmaf(w0, f0b.y, a3);
        }
        b += c;
    }

    zl += __shfl_xor(zl, 1, 32);
    zl += __shfl_xor(zl, 2, 32);
    zl += __shfl_xor(zl, 4, 32);
    zl += __shfl_xor(zl, 8, 32);
    const float z = wself + zl;

    float zi = 1.f / z;
    a0 *= zi; a1 *= zi; a2 *= zi; a3 *= zi;
    a0 = 0.5f * (a0 + __shfl_xor(a0, 16));
    a1 = 0.5f * (a1 + __shfl_xor(a1, 16));
    a2 = 0.5f * (a2 + __shfl_xor(a2, 16));
    a3 = 0.5f * (a3 + __shfl_xor(a3, 16));
    if (hs == 0) {
        float4 bv = *(const float4*)&bias[ch];
        a0 += bv.x; a1 += bv.y; a2 += bv.z; a3 += bv.w;
        a0 = a0 > 0.f ? a0 : 0.f;
        a1 = a1 > 0.f ? a1 : 0.f;
        a2 = a2 > 0.f ? a2 : 0.f;
        a3 = a3 > 0.f ? a3 : 0.f;
        __align__(8) __half2 hp[2];
        hp[0] = __floats2half2_rn(a0, a1);
        hp[1] = __floats2half2_rn(a2, a3);
        if constexpr (WRITER == 0) {
            *(uint2*)&out[(size_t)n * 64 + ch] = *(uint2*)hp;
        } else {
            // LDS store in the MFMA x-fragment layout: phase = ch>>5, 64 B rows,
            // 16-B-granule XOR swizzle ((row&3)<<4); 8-B chunk stays contiguous.
            int ph = ch >> 5;
            int cc = ch & 31;
            int byt = ph * (GBM2 * 64) + row_local * 64 + ((cc * 2) ^ ((row_local & 3) << 4));
            *(uint2*)(featlds + byt) = *(uint2*)hp;
        }
    }
}

// standalone attention (layer-2 / fallback layer-1): blocks cover 8 nodes each
__global__ __launch_bounds__(256)
void k_att2x(const __half* __restrict__ h_l, const __half* __restrict__ h_r,
             const float* __restrict__ ssrc_l, const float* __restrict__ sdst_l,
             const float* __restrict__ ssrc_r, const float* __restrict__ sdst_r,
             const int* __restrict__ cnt_l, const int* __restrict__ csr_l,
             const int* __restrict__ cnt_r, const int* __restrict__ csr_r,
             const float* __restrict__ bias_l, const float* __restrict__ bias_r,
             __half* __restrict__ feat_l, __half* __restrict__ feat_r) {
    int blk = blockIdx.x;
    bool right = blk >= AB2;
    int n = (blk - (right ? AB2 : 0)) * 8 + (threadIdx.x >> 5);
    if (!right) att_body_t<0>(n, 0, h_l, ssrc_l, sdst_l, cnt_l, csr_l, bias_l, feat_l, nullptr);
    else        att_body_t<0>(n, 0, h_r, ssrc_r, sdst_r, cnt_r, csr_r, bias_r, feat_r, nullptr);
}

// ---------------- FUSED att1 + gemm2: 64-row blocks ----------------------------
// Block computes layer-1 attention for its 64 rows into LDS (MFMA layout),
// then runs the layer-2 MFMA directly from LDS. Writes h2/ss2 (double buffer —
// other blocks may still be gathering layer-1 h).
__global__ __launch_bounds__(256)
void k_att1gemm2(const __half* __restrict__ h1_l, const __half* __restrict__ h1_r,
                 const float* __restrict__ ss1_l, const float* __restrict__ sd1_l,
                 const float* __restrict__ ss1_r, const float* __restrict__ sd1_r,
                 const int* __restrict__ cnt_l, const int* __restrict__ csr_l,
                 const int* __restrict__ cnt_r, const int* __restrict__ csr_r,
                 const float* __restrict__ b1l, const float* __restrict__ b1r,
                 const __half* __restrict__ wi2l, const float* __restrict__ as2l,
                 const float* __restrict__ ad2l,
                 const __half* __restrict__ wi2r, const float* __restrict__ as2r,
                 const float* __restrict__ ad2r,
                 __half* __restrict__ h2_l, __half* __restrict__ h2_r,
                 float* __restrict__ ss2_l, float* __restrict__ sd2_l,
                 float* __restrict__ ss2_r, float* __restrict__ sd2_r) {
    __shared__ __align__(16) char smem[GBM2 * 64 * 2 + 16384];  // feat 8K | wh 8K | wl 8K
    char* const featp = smem;
    char* const wh = smem + GBM2 * 64 * 2;
    char* const wl = wh + 8192;

    int b = blockIdx.x;
    const bool right = b >= GB2;
    const int bid = right ? b - GB2 : b;
    const int row0 = bid * GBM2;

    const __half* __restrict__ h1   = right ? h1_r : h1_l;
    const float* __restrict__ ss1   = right ? ss1_r : ss1_l;
    const float* __restrict__ sd1   = right ? sd1_r : sd1_l;
    const int* __restrict__ cnt     = right ? cnt_r : cnt_l;
    const int* __restrict__ csr     = right ? csr_r : csr_l;
    const float* __restrict__ bias1 = right ? b1r : b1l;
    const __half* __restrict__ Wimg = right ? wi2r : wi2l;
    const float* __restrict__ a_src = right ? as2r : as2l;
    const float* __restrict__ a_dst = right ? ad2r : ad2l;
    __half* __restrict__ h2         = right ? h2_r : h2_l;
    float* __restrict__ ss2         = right ? ss2_r : ss2_l;
    float* __restrict__ sd2         = right ? sd2_r : sd2_l;

    const int tid = threadIdx.x;

    // tail block: zero feat LDS so garbage rows can't poison (rows >= NN unused)
    if (row0 + GBM2 > NN) {
        for (int i = tid; i < (GBM2 * 64 * 2) / 16; i += 256)
            ((uint4*)featp)[i] = make_uint4(0, 0, 0, 0);
        __syncthreads();
    }

    // att phase: 8 rounds x 8 nodes (32-lane group per node)
    #pragma unroll 1
    for (int it = 0; it < GBM2 / 8; ++it) {
        int nl = it * 8 + (tid >> 5);
        int n = row0 + nl;
        if (n < NN)
            att_body_t<1>(n, nl, h1, ss1, sd1, cnt, csr, bias1, nullptr, featp);
    }
    __syncthreads();

    // gemm phase (K=64, fp16, x already in LDS)
    const int wid = tid >> 6;
    const int lane = tid & 63;
    const int l15 = lane & 15;
    const int lg = lane >> 4;

    f32x4 acc[8];
    #pragma unroll
    for (int j = 0; j < 8; ++j) acc[j] = (f32x4)0.f;

    #pragma unroll
    for (int kp = 0; kp < 2; ++kp) {
        if (kp) __syncthreads();   // protect wh/wl reuse
        {
            const uint4* ws = (const uint4*)((const char*)Wimg + (size_t)kp * 16384);
            uint4* wd = (uint4*)wh;
            #pragma unroll
            for (int i = 0; i < 4; ++i) wd[tid + i * 256] = ws[tid + i * 256];
        }
        __syncthreads();

        const int koff = lg * 16;
        int row = wid * 16 + l15;
        f16x8 ah = *(const f16x8*)(featp + kp * (GBM2 * 64) + row * 64 +
                                   (koff ^ ((row & 3) << 4)));
        #pragma unroll
        for (int ct = 0; ct < 8; ++ct) {
            int col = ct * 16 + l15;
            int byt = col * 64 + (koff ^ ((col & 3) << 4));
            f16x8 bh = *(const f16x8*)(wh + byt);
            f16x8 bl = *(const f16x8*)(wl + byt);
            acc[ct] = __builtin_amdgcn_mfma_f32_16x16x32_f16(ah, bh, acc[ct], 0, 0, 0);
            acc[ct] = __builtin_amdgcn_mfma_f32_16x16x32_f16(ah, bl, acc[ct], 0, 0, 0);
        }
    }

    float sv[8], dv[8];
    #pragma unroll
    for (int ct = 0; ct < 8; ++ct) {
        sv[ct] = a_src[ct * 16 + l15];
        dv[ct] = a_dst[ct * 16 + l15];
    }
    #pragma unroll
    for (int r = 0; r < 4; ++r) {
        int row = row0 + wid * 16 + lg * 4 + r;
        bool ok = row < NN;
        if (ok) {
            #pragma unroll
            for (int ct = 0; ct < 8; ++ct)
                h2[(size_t)row * 128 + ct * 16 + l15] = __float2half(acc[ct][r]);
        }
        float ps0 = 0.f, pd0 = 0.f, ps1 = 0.f, pd1 = 0.f;
        #pragma unroll
        for (int ct = 0; ct < 4; ++ct) {
            ps0 = fmaf(acc[ct][r], sv[ct], ps0);
            pd0 = fmaf(acc[ct][r], dv[ct], pd0);
            ps1 = fmaf(acc[ct + 4][r], sv[ct + 4], ps1);
            pd1 = fmaf(acc[ct + 4][r], dv[ct + 4], pd1);
        }
        ps0 += __shfl_xor(ps0, 1); pd0 += __shfl_xor(pd0, 1);
        ps1 += __shfl_xor(ps1, 1); pd1 += __shfl_xor(pd1, 1);
        ps0 += __shfl_xor(ps0, 2); pd0 += __shfl_xor(pd0, 2);
        ps1 += __shfl_xor(ps1, 2); pd1 += __shfl_xor(pd1, 2);
        ps0 += __shfl_xor(ps0, 4); pd0 += __shfl_xor(pd0, 4);
        ps1 += __shfl_xor(ps1, 4); pd1 += __shfl_xor(pd1, 4);
        ps0 += __shfl_xor(ps0, 8); pd0 += __shfl_xor(pd0, 8);
        ps1 += __shfl_xor(ps1, 8); pd1 += __shfl_xor(pd1, 8);
        if (ok && l15 == 0) {
            ss2[row * 2 + 0] = ps0;
            ss2[row * 2 + 1] = ps1;
            sd2[row * 2 + 0] = pd0;
            sd2[row * 2 + 1] = pd1;
        }
    }
}

// ---------------- merge + FC1 + FC2 ----------------
__global__ __launch_bounds__(256)
void k_fc(const __half* __restrict__ fl, const __half* __restrict__ fr,
          const int* __restrict__ ll, const int* __restrict__ lr,
          const float* __restrict__ w1, const float* __restrict__ b1,
          const float* __restrict__ w2, const float* __restrict__ b2,
          float* __restrict__ out) {
    int b = blockIdx.x * 4 + (threadIdx.x >> 6);
    int j = threadIdx.x & 63;
    int la = ll[b], lb = lr[b];
    float v0 = __half2float(fl[(size_t)la * 64 + j]);
    float v1 = __half2float(fr[(size_t)lb * 64 + j]);
    float acc = b1[j];
    #pragma unroll 8
    for (int k = 0; k < 64; ++k)
        acc += __shfl(v0, k, 64) * w1[k * 64 + j];
    #pragma unroll 8
    for (int k = 0; k < 64; ++k)
        acc += __shfl(v1, k, 64) * w1[(64 + k) * 64 + j];
    float x1 = acc > 0.f ? acc : 0.f;
    float p0 = x1 * w2[j * 2 + 0];
    float p1 = x1 * w2[j * 2 + 1];
    #pragma unroll
    for (int o = 32; o >= 1; o >>= 1) {
        p0 += __shfl_xor(p0, o, 64);
        p1 += __shfl_xor(p1, o, 64);
    }
    if (j == 0) {
        out[b * 2 + 0] = p0 + b2[0];
        out[b * 2 + 1] = p1 + b2[1];
    }
}

extern "C" void kernel_launch(void* const* d_in, const int* in_sizes, int n_in,
                              void* d_out, int out_size, void* d_ws, size_t ws_size,
                              hipStream_t stream) {
    const float* x_l  = (const float*)d_in[0];
    const float* x_r  = (const float*)d_in[1];
    const int* ei_l  = (const int*)d_in[2];
    const int* ei_r  = (const int*)d_in[3];
    const int* lab_l = (const int*)d_in[4];
    const int* lab_r = (const int*)d_in[5];
    const float* w1l  = (const float*)d_in[6];
    const float* as1l = (const float*)d_in[7];
    const float* ad1l = (const float*)d_in[8];
    const float* b1l  = (const float*)d_in[9];
    const float* w2l  = (const float*)d_in[10];
    const float* as2l = (const float*)d_in[11];
    const float* ad2l = (const float*)d_in[12];
    const float* b2l  = (const float*)d_in[13];
    const float* w1r  = (const float*)d_in[14];
    const float* as1r = (const float*)d_in[15];
    const float* ad1r = (const float*)d_in[16];
    const float* b1r  = (const float*)d_in[17];
    const float* w2r  = (const float*)d_in[18];
    const float* as2r = (const float*)d_in[19];
    const float* ad2r = (const float*)d_in[20];
    const float* b2r  = (const float*)d_in[21];
    const float* fc1w = (const float*)d_in[22];
    const float* fc1b = (const float*)d_in[23];
    const float* fc2w = (const float*)d_in[24];
    const float* fc2b = (const float*)d_in[25];

    char* p = (char*)d_ws;
    auto alloc = [&](size_t bytes) -> void* {
        void* q = (void*)p;
        p += (bytes + 255) & ~(size_t)255;
        return q;
    };

    // ---- fused-path carve (~149 MB): h1 + h2 double buffer ----
    __half* h_l    = (__half*)alloc((size_t)NN * 128 * 2);
    __half* h_r    = (__half*)alloc((size_t)NN * 128 * 2);
    __half* h2_l   = (__half*)alloc((size_t)NN * 128 * 2);
    __half* h2_r   = (__half*)alloc((size_t)NN * 128 * 2);
    float* ssrc_l = (float*)alloc((size_t)NN * 2 * 4);
    float* sdst_l = (float*)alloc((size_t)NN * 2 * 4);
    float* ssrc_r = (float*)alloc((size_t)NN * 2 * 4);
    float* sdst_r = (float*)alloc((size_t)NN * 2 * 4);
    float* ss2_l  = (float*)alloc((size_t)NN * 2 * 4);
    float* sd2_l  = (float*)alloc((size_t)NN * 2 * 4);
    float* ss2_r  = (float*)alloc((size_t)NN * 2 * 4);
    float* sd2_r  = (float*)alloc((size_t)NN * 2 * 4);
    int* cnt2  = (int*)alloc(((size_t)2 * NN + 2 * NB) * 4);
    int* csr_l = (int*)alloc((size_t)NN * PAD * 4);
    int* csr_r = (int*)alloc((size_t)NN * PAD * 4);
    __half* wi1l = (__half*)alloc(65536);
    __half* wi1r = (__half*)alloc(65536);
    __half* wi2l = (__half*)alloc(32768);
    __half* wi2r = (__half*)alloc(32768);
    int* cnt_l = cnt2;
    int* cnt_r = cnt2 + NN;
    int* gcur  = cnt2 + 2 * NN;

    const bool fused = (size_t)(p - (char*)d_ws) <= ws_size;

    if (fused) {
        // buf (16 MB) overlays h2_l (dead until k_att1gemm2); final feat overlays h1
        int* buf = (int*)h2_l;
        __half* featF_l = h_l;
        __half* featF_r = h_r;

        hipMemsetAsync(gcur, 0, (size_t)2 * NB * 4, stream);

        k_bucket<<<2 * NCH + 12, 256, 0, stream>>>(ei_l, ei_r, buf, gcur,
                                                   w1l, w1r, w2l, w2r,
                                                   wi1l, wi1r, wi2l, wi2r);

        k_csr_gemm1<<<2 * NB + 2 * GB, 256, 0, stream>>>(
            buf, gcur, cnt_l, cnt_r, csr_l, csr_r,
            x_l, x_r, wi1l, as1l, ad1l, wi1r, as1r, ad1r,
            h_l, h_r, ssrc_l, sdst_l, ssrc_r, sdst_r);

        // fused layer-1 attention + layer-2 GEMM (feat stays in LDS)
        k_att1gemm2<<<2 * GB2, 256, 0, stream>>>(
            h_l, h_r, ssrc_l, sdst_l, ssrc_r, sdst_r,
            cnt_l, csr_l, cnt_r, csr_r, b1l, b1r,
            wi2l, as2l, ad2l, wi2r, as2r, ad2r,
            h2_l, h2_r, ss2_l, sd2_l, ss2_r, sd2_r);

        // layer-2 attention (reads h2/ss2; writes final feat over dead h1)
        k_att2x<<<2 * AB2, 256, 0, stream>>>(h2_l, h2_r, ss2_l, sd2_l, ss2_r, sd2_r,
                                             cnt_l, csr_l, cnt_r, csr_r,
                                             b2l, b2r, featF_l, featF_r);

        k_fc<<<(BB + 3) / 4, 256, 0, stream>>>(featF_l, featF_r, lab_l, lab_r,
                                               fc1w, fc1b, fc2w, fc2b,
                                               (float*)d_out);
        return;
    }

    // ---- fallback: round-15 schedule (~119 MB carve) ----
    p = (char*)d_ws;
    h_l    = (__half*)alloc((size_t)NN * 128 * 2);
    h_r    = (__half*)alloc((size_t)NN * 128 * 2);
    __half* feat_l = (__half*)alloc((size_t)NN * 64 * 2);
    __half* feat_r = (__half*)alloc((size_t)NN * 64 * 2);
    ssrc_l = (float*)alloc((size_t)NN * 2 * 4);
    sdst_l = (float*)alloc((size_t)NN * 2 * 4);
    ssrc_r = (float*)alloc((size_t)NN * 2 * 4);
    sdst_r = (float*)alloc((size_t)NN * 2 * 4);
    cnt2  = (int*)alloc(((size_t)2 * NN + 2 * NB) * 4);
    csr_l = (int*)alloc((size_t)NN * PAD * 4);
    csr_r = (int*)alloc((size_t)NN * PAD * 4);
    wi1l = (__half*)alloc(65536);
    wi1r = (__half*)alloc(65536);
    wi2l = (__half*)alloc(32768);
    wi2r = (__half*)alloc(32768);
    cnt_l = cnt2;
    cnt_r = cnt2 + NN;
    gcur  = cnt2 + 2 * NN;
    int* buf = (int*)feat_l;

    hipMemsetAsync(gcur, 0, (size_t)2 * NB * 4, stream);

    k_bucket<<<2 * NCH + 12, 256, 0, stream>>>(ei_l, ei_r, buf, gcur,
                                               w1l, w1r, w2l, w2r,
                                               wi1l, wi1r, wi2l, wi2r);

    k_csr_gemm1<<<2 * NB + 2 * GB, 256, 0, stream>>>(
        buf, gcur, cnt_l, cnt_r, csr_l, csr_r,
        x_l, x_r, wi1l, as1l, ad1l, wi1r, as1r, ad1r,
        h_l, h_r, ssrc_l, sdst_l, ssrc_r, sdst_r);

    k_att2x<<<2 * AB2, 256, 0, stream>>>(h_l, h_r, ssrc_l, sdst_l, ssrc_r, sdst_r,
                                         cnt_l, csr_l, cnt_r, csr_r,
                                         b1l, b1r, feat_l, feat_r);

    k_gemm2x<<<2 * GB, 256, 0, stream>>>(feat_l, feat_r,
                                         wi2l, as2l, ad2l, wi2r, as2r, ad2r,
                                         h_l, h_r, ssrc_l, sdst_l, ssrc_r, sdst_r);

    k_att2x<<<2 * AB2, 256, 0, stream>>>(h_l, h_r, ssrc_l, sdst_l, ssrc_r, sdst_r,
                                         cnt_l, csr_l, cnt_r, csr_r,
                                         b2l, b2r, feat_l, feat_r);

    k_fc<<<(BB + 3) / 4, 256, 0, stream>>>(feat_l, feat_r, lab_l, lab_r,
                                           fc1w, fc1b, fc2w, fc2b,
                                           (float*)d_out);
}

// Round 17
// 589.274 us; speedup vs baseline: 1.0152x; 1.0152x over previous
//
#include <hip/hip_runtime.h>
#include <hip/hip_bf16.h>
#include <hip/hip_fp16.h>

// Problem constants (GATPair_38800734552870) — all float tensors are fp32.
constexpr int NN   = 100000;   // nodes
constexpr int EE   = 1600000;  // edges
constexpr int BB   = 8192;
constexpr int PAD  = 48;       // padded CSR stride
constexpr float NEG_SLOPE = 0.2f;

constexpr int GBM = 128;                 // rows per gemm block
constexpr int GB = (NN + GBM - 1) / GBM; // 782 gemm blocks per tower
constexpr int AB2 = NN / 8;              // 12500 att blocks per tower (8 nodes/block)

// two-phase coalesced CSR build (counting sort by 256-node bucket)
constexpr int BSPAN = 256;
constexpr int NB    = (NN + BSPAN - 1) / BSPAN;   // 391 buckets per side
constexpr int BCAP  = 5120;
constexpr int CHA   = 2048;
constexpr int NCH   = (EE + CHA - 1) / CHA;       // 782 chunks per side
constexpr int XSB   = 512;                        // x-split blocks (main path)

typedef _Float16 f16x8 __attribute__((ext_vector_type(8)));
typedef _Float16 f16x4 __attribute__((ext_vector_type(4)));
typedef float    f32x4 __attribute__((ext_vector_type(4)));

__device__ __forceinline__ float4 ld4(const float* p) { return *(const float4*)p; }

// ================= shared GEMM epilogue (h store + fused scores) ===============
__device__ __forceinline__
void gemm_epilogue(int row0, int wid, int l15, int lg,
                   f32x4 (&acc)[2][8],
                   const float* __restrict__ a_src, const float* __restrict__ a_dst,
                   __half* __restrict__ h,
                   float* __restrict__ ssrc, float* __restrict__ sdst) {
    float sv[8], dv[8];
    #pragma unroll
    for (int ct = 0; ct < 8; ++ct) {
        sv[ct] = a_src[ct * 16 + l15];
        dv[ct] = a_dst[ct * 16 + l15];
    }
    #pragma unroll
    for (int rt = 0; rt < 2; ++rt) {
        #pragma unroll
        for (int r = 0; r < 4; ++r) {
            int row = row0 + wid * 32 + rt * 16 + lg * 4 + r;
            bool ok = row < NN;
            if (ok) {
                #pragma unroll
                for (int ct = 0; ct < 8; ++ct)
                    h[(size_t)row * 128 + ct * 16 + l15] = __float2half(acc[rt][ct][r]);
            }
            float ps0 = 0.f, pd0 = 0.f, ps1 = 0.f, pd1 = 0.f;
            #pragma unroll
            for (int ct = 0; ct < 4; ++ct) {
                ps0 = fmaf(acc[rt][ct][r], sv[ct], ps0);
                pd0 = fmaf(acc[rt][ct][r], dv[ct], pd0);
                ps1 = fmaf(acc[rt][ct + 4][r], sv[ct + 4], ps1);
                pd1 = fmaf(acc[rt][ct + 4][r], dv[ct + 4], pd1);
            }
            ps0 += __shfl_xor(ps0, 1); pd0 += __shfl_xor(pd0, 1);
            ps1 += __shfl_xor(ps1, 1); pd1 += __shfl_xor(pd1, 1);
            ps0 += __shfl_xor(ps0, 2); pd0 += __shfl_xor(pd0, 2);
            ps1 += __shfl_xor(ps1, 2); pd1 += __shfl_xor(pd1, 2);
            ps0 += __shfl_xor(ps0, 4); pd0 += __shfl_xor(pd0, 4);
            ps1 += __shfl_xor(ps1, 4); pd1 += __shfl_xor(pd1, 4);
            ps0 += __shfl_xor(ps0, 8); pd0 += __shfl_xor(pd0, 8);
            ps1 += __shfl_xor(ps1, 8); pd1 += __shfl_xor(pd1, 8);
            if (ok && l15 == 0) {
                ssrc[row * 2 + 0] = ps0;
                ssrc[row * 2 + 1] = ps1;
                sdst[row * 2 + 0] = pd0;
                sdst[row * 2 + 1] = pd1;
            }
        }
    }
}

// ---------------- GEMM body (fp32 input, in-kernel split — FALLBACK; or fp16) ---
template <typename TIN, int K>
__device__ __forceinline__
void gemm_mfma_body(int bid, const TIN* __restrict__ x,
                    const __half* __restrict__ Wimg,
                    const float* __restrict__ a_src, const float* __restrict__ a_dst,
                    __half* __restrict__ h,
                    float* __restrict__ ssrc, float* __restrict__ sdst,
                    char* lds) {
    constexpr bool HAS_LO = sizeof(TIN) == 4;
    char* const xh = lds;
    char* const xl = HAS_LO ? (lds + 8192) : lds;
    char* const wh = lds + (HAS_LO ? 16384 : 8192);
    char* const wl = wh + 8192;

    const int tid = threadIdx.x;
    const int wid = tid >> 6;
    const int lane = tid & 63;
    const int l15 = lane & 15;
    const int lg = lane >> 4;
    const int row0 = bid * GBM;

    f32x4 acc[2][8];
    #pragma unroll
    for (int i = 0; i < 2; ++i)
        #pragma unroll
        for (int j = 0; j < 8; ++j) acc[i][j] = (f32x4)0.f;

    for (int kt = 0; kt < K; kt += 32) {
        __syncthreads();
        if constexpr (HAS_LO) {
            #pragma unroll
            for (int i = 0; i < 4; ++i) {
                int idx = tid + i * 256;
                int row = idx >> 3, c4 = idx & 7;
                int grow = row0 + row; if (grow >= NN) grow = NN - 1;
                float4 v = ld4(&x[(size_t)grow * K + kt + c4 * 4]);
                f16x4 hv, lv;
                float f0 = v.x; _Float16 h0 = (_Float16)f0; hv[0] = h0; lv[0] = (_Float16)(f0 - (float)h0);
                float f1 = v.y; _Float16 h1 = (_Float16)f1; hv[1] = h1; lv[1] = (_Float16)(f1 - (float)h1);
                float f2 = v.z; _Float16 h2 = (_Float16)f2; hv[2] = h2; lv[2] = (_Float16)(f2 - (float)h2);
                float f3 = v.w; _Float16 h3 = (_Float16)f3; hv[3] = h3; lv[3] = (_Float16)(f3 - (float)h3);
                int byt = row * 64 + ((c4 * 8) ^ ((row & 3) << 4));
                *(f16x4*)(xh + byt) = hv;
                *(f16x4*)(xl + byt) = lv;
            }
        } else {
            #pragma unroll
            for (int i = 0; i < 2; ++i) {
                int idx = tid + i * 256;
                int row = idx >> 2, c8 = idx & 3;
                int grow = row0 + row; if (grow >= NN) grow = NN - 1;
                uint4 v = *(const uint4*)&x[(size_t)grow * 64 + kt + c8 * 8];
                int byt = row * 64 + ((c8 * 16) ^ ((row & 3) << 4));
                *(uint4*)(xh + byt) = v;
            }
        }
        {
            const uint4* ws = (const uint4*)((const char*)Wimg + (size_t)(kt >> 5) * 16384);
            uint4* wd = (uint4*)wh;
            #pragma unroll
            for (int i = 0; i < 4; ++i) wd[tid + i * 256] = ws[tid + i * 256];
        }
        __syncthreads();

        const int koff = lg * 16;
        f16x8 ah[2], al[2];
        #pragma unroll
        for (int rt = 0; rt < 2; ++rt) {
            int row = wid * 32 + rt * 16 + l15;
            int byt = row * 64 + (koff ^ ((row & 3) << 4));
            ah[rt] = *(const f16x8*)(xh + byt);
            if constexpr (HAS_LO) al[rt] = *(const f16x8*)(xl + byt);
        }
        #pragma unroll
        for (int ct = 0; ct < 8; ++ct) {
            int col = ct * 16 + l15;
            int byt = col * 64 + (koff ^ ((col & 3) << 4));
            f16x8 bh = *(const f16x8*)(wh + byt);
            f16x8 bl = *(const f16x8*)(wl + byt);
            #pragma unroll
            for (int rt = 0; rt < 2; ++rt) {
                acc[rt][ct] = __builtin_amdgcn_mfma_f32_16x16x32_f16(ah[rt], bh, acc[rt][ct], 0, 0, 0);
                acc[rt][ct] = __builtin_amdgcn_mfma_f32_16x16x32_f16(ah[rt], bl, acc[rt][ct], 0, 0, 0);
                if constexpr (HAS_LO)
                    acc[rt][ct] = __builtin_amdgcn_mfma_f32_16x16x32_f16(al[rt], bh, acc[rt][ct], 0, 0, 0);
            }
        }
    }
    gemm_epilogue(row0, wid, l15, lg, acc, a_src, a_dst, h, ssrc, sdst);
}

// ---------------- GEMM body (pre-split xh/xl fp16 arrays — MAIN path) ----------
__device__ __forceinline__
void gemm_ps_body(int bid, const _Float16* __restrict__ xh_g,
                  const _Float16* __restrict__ xl_g,
                  const __half* __restrict__ Wimg,
                  const float* __restrict__ a_src, const float* __restrict__ a_dst,
                  __half* __restrict__ h,
                  float* __restrict__ ssrc, float* __restrict__ sdst,
                  char* lds) {
    char* const xh = lds;
    char* const xl = lds + 8192;
    char* const wh = lds + 16384;
    char* const wl = wh + 8192;

    const int tid = threadIdx.x;
    const int wid = tid >> 6;
    const int lane = tid & 63;
    const int l15 = lane & 15;
    const int lg = lane >> 4;
    const int row0 = bid * GBM;

    f32x4 acc[2][8];
    #pragma unroll
    for (int i = 0; i < 2; ++i)
        #pragma unroll
        for (int j = 0; j < 8; ++j) acc[i][j] = (f32x4)0.f;

    for (int kt = 0; kt < 128; kt += 32) {
        __syncthreads();
        // x staging: pure uint4 copies (conversion pre-done in k_bucket xsplit)
        #pragma unroll
        for (int i = 0; i < 2; ++i) {
            int idx = tid + i * 256;              // 512 uint4 per buffer
            int row = idx >> 2, c8 = idx & 3;
            int grow = row0 + row; if (grow >= NN) grow = NN - 1;
            size_t src = (size_t)grow * 128 + kt + c8 * 8;
            int byt = row * 64 + ((c8 * 16) ^ ((row & 3) << 4));
            *(uint4*)(xh + byt) = *(const uint4*)&xh_g[src];
            *(uint4*)(xl + byt) = *(const uint4*)&xl_g[src];
        }
        {
            const uint4* ws = (const uint4*)((const char*)Wimg + (size_t)(kt >> 5) * 16384);
            uint4* wd = (uint4*)wh;
            #pragma unroll
            for (int i = 0; i < 4; ++i) wd[tid + i * 256] = ws[tid + i * 256];
        }
        __syncthreads();

        const int koff = lg * 16;
        f16x8 ah[2], al[2];
        #pragma unroll
        for (int rt = 0; rt < 2; ++rt) {
            int row = wid * 32 + rt * 16 + l15;
            int byt = row * 64 + (koff ^ ((row & 3) << 4));
            ah[rt] = *(const f16x8*)(xh + byt);
            al[rt] = *(const f16x8*)(xl + byt);
        }
        #pragma unroll
        for (int ct = 0; ct < 8; ++ct) {
            int col = ct * 16 + l15;
            int byt = col * 64 + (koff ^ ((col & 3) << 4));
            f16x8 bh = *(const f16x8*)(wh + byt);
            f16x8 bl = *(const f16x8*)(wl + byt);
            #pragma unroll
            for (int rt = 0; rt < 2; ++rt) {
                acc[rt][ct] = __builtin_amdgcn_mfma_f32_16x16x32_f16(ah[rt], bh, acc[rt][ct], 0, 0, 0);
                acc[rt][ct] = __builtin_amdgcn_mfma_f32_16x16x32_f16(ah[rt], bl, acc[rt][ct], 0, 0, 0);
                acc[rt][ct] = __builtin_amdgcn_mfma_f32_16x16x32_f16(al[rt], bh, acc[rt][ct], 0, 0, 0);
            }
        }
    }
    gemm_epilogue(row0, wid, l15, lg, acc, a_src, a_dst, h, ssrc, sdst);
}

// ---------------- phase A: bucket sort (+ W-image prep, + x-split blocks) -------
__global__ __launch_bounds__(256)
void k_bucket(const int* __restrict__ el, const int* __restrict__ er,
              int* __restrict__ buf, int* __restrict__ gcur,
              const float* __restrict__ w1l, const float* __restrict__ w1r,
              const float* __restrict__ w2l, const float* __restrict__ w2r,
              __half* __restrict__ wi1l, __half* __restrict__ wi1r,
              __half* __restrict__ wi2l, __half* __restrict__ wi2r,
              const float* __restrict__ x_l, const float* __restrict__ x_r,
              _Float16* __restrict__ xh_l, _Float16* __restrict__ xl_l,
              _Float16* __restrict__ xh_r, _Float16* __restrict__ xl_r) {
    const int blk0 = blockIdx.x;
    if (blk0 >= 2 * NCH + 12) {
        // ---- x-split: fp32 -> (hi, lo) fp16 arrays, streamed (main path only) --
        const size_t TOT4 = (size_t)NN * 128 / 4;   // float4 per tower
        for (size_t i = (size_t)(blk0 - (2 * NCH + 12)) * 256 + threadIdx.x;
             i < 2 * TOT4; i += (size_t)XSB * 256) {
            bool rt = i >= TOT4;
            size_t j = rt ? i - TOT4 : i;
            const float* xp = rt ? x_r : x_l;
            _Float16* xhp = rt ? xh_r : xh_l;
            _Float16* xlp = rt ? xl_r : xl_l;
            float4 v = ld4(&xp[j * 4]);
            f16x4 hv, lv;
            float f0 = v.x; _Float16 h0 = (_Float16)f0; hv[0] = h0; lv[0] = (_Float16)(f0 - (float)h0);
            float f1 = v.y; _Float16 h1 = (_Float16)f1; hv[1] = h1; lv[1] = (_Float16)(f1 - (float)h1);
            float f2 = v.z; _Float16 h2 = (_Float16)f2; hv[2] = h2; lv[2] = (_Float16)(f2 - (float)h2);
            float f3 = v.w; _Float16 h3 = (_Float16)f3; hv[3] = h3; lv[3] = (_Float16)(f3 - (float)h3);
            *(f16x4*)&xhp[j * 4] = hv;
            *(f16x4*)&xlp[j * 4] = lv;
        }
        return;
    }
    if (blk0 >= 2 * NCH) {
        const int id = blk0 - 2 * NCH;
        const float* W;
        __half* img;
        int kt;
        if (id < 8) {
            W = (id >> 2) ? w1r : w1l;
            img = ((id >> 2) ? wi1r : wi1l) + (size_t)(id & 3) * 8192;
            kt = (id & 3) * 32;
        } else {
            int jx = id - 8;
            W = (jx >> 1) ? w2r : w2l;
            img = ((jx >> 1) ? wi2r : wi2l) + (size_t)(jx & 1) * 8192;
            kt = (jx & 1) * 32;
        }
        _Float16* imgh = (_Float16*)img;
        _Float16* imgl = imgh + 4096;
        for (int i = threadIdx.x; i < 4096; i += 256) {
            int kk = i >> 7, col = i & 127;
            float f = W[(size_t)(kt + kk) * 128 + col];
            _Float16 hi = (_Float16)f;
            _Float16 lo = (_Float16)(f - (float)hi);
            int hidx = col * 32 + (kk ^ ((col & 3) << 3));
            imgh[hidx] = hi;
            imgl[hidx] = lo;
        }
        return;
    }

    __shared__ int   P1[CHA];
    __shared__ short bkof[CHA];
    __shared__ int hist[NB];
    __shared__ int st[NB];
    __shared__ int ofs[NB];
    __shared__ int base[NB];
    __shared__ int sc[512];

    const int blk = blk0;
    const bool right = blk >= NCH;
    const int* __restrict__ e = right ? er : el;
    const int sideoff = right ? NB : 0;
    const int cbase = (right ? blk - NCH : blk) * CHA;
    int cnum = EE - cbase; if (cnum > CHA) cnum = CHA;
    const int t = threadIdx.x;

    for (int i = t; i < NB; i += 256) hist[i] = 0;
    __syncthreads();
    for (int i = t; i < cnum; i += 256) {
        int d = e[EE + cbase + i];
        atomicAdd(&hist[d >> 8], 1);
    }
    __syncthreads();

    sc[t]       = (t < NB)       ? hist[t]       : 0;
    sc[t + 256] = (t + 256 < NB) ? hist[t + 256] : 0;
    __syncthreads();
    for (int off = 1; off < 512; off <<= 1) {
        int a0 = sc[t];
        int a1 = sc[t + 256];
        int b0 = (t >= off)       ? sc[t - off]       : 0;
        int b1 = (t + 256 >= off) ? sc[t + 256 - off] : 0;
        __syncthreads();
        sc[t] = a0 + b0;
        sc[t + 256] = a1 + b1;
        __syncthreads();
    }
    for (int i = t; i < NB; i += 256) {
        int s = sc[i] - hist[i];
        st[i] = s;
        ofs[i] = s;
    }
    __syncthreads();
    for (int i = t; i < cnum; i += 256) {
        int d = e[EE + cbase + i];
        int s = e[cbase + i];
        int bk = d >> 8;
        int pos = atomicAdd(&ofs[bk], 1);
        P1[pos] = (s << 8) | (d & 255);
        bkof[pos] = (short)bk;
    }
    __syncthreads();
    for (int i = t; i < NB; i += 256)
        base[i] = hist[i] ? atomicAdd(&gcur[sideoff + i], hist[i]) : 0;
    __syncthreads();
    for (int j = t; j < cnum; j += 256) {
        int bk = bkof[j];
        buf[(size_t)(sideoff + bk) * BCAP + base[bk] + (j - st[bk])] = P1[j];
    }
}

// ---------------- phase B body: per-bucket mini-CSR in LDS, coalesced writeout --
__device__ __forceinline__
void csr_body(int blk, const int* __restrict__ buf, const int* __restrict__ gcur,
              int* __restrict__ cntl, int* __restrict__ cntr,
              int* __restrict__ csrl, int* __restrict__ csrr, char* smem) {
    int* lcnt = (int*)smem;
    int* lcsr = (int*)(smem + 1024);

    const bool right = blk >= NB;
    const int bk = right ? blk - NB : blk;
    int* __restrict__ cnt = right ? cntr : cntl;
    int* __restrict__ csr = right ? csrr : csrl;
    const int* __restrict__ src = buf + (size_t)blk * BCAP;
    const int count = gcur[blk];
    const int lo = bk * BSPAN;
    int nn = NN - lo; if (nn > BSPAN) nn = BSPAN;
    const int t = threadIdx.x;

    for (int i = t; i < nn; i += 256) lcnt[i] = 0;
    __syncthreads();
    for (int i = t; i < count; i += 256) {
        int v = src[i];
        int ld = v & 255;
        int s  = (int)((unsigned)v >> 8);
        int slot = atomicAdd(&lcnt[ld], 1);
        lcsr[ld * PAD + slot] = s;
    }
    __syncthreads();
    const int tot4 = (nn * PAD) >> 2;
    int4* __restrict__ dst4 = (int4*)&csr[(size_t)lo * PAD];
    const int4* __restrict__ s4 = (const int4*)lcsr;
    for (int i = t; i < tot4; i += 256) dst4[i] = s4[i];
    for (int i = t; i < nn; i += 256) cnt[lo + i] = lcnt[i];
}

// ---------------- fused: CSR build || layer-1 GEMMs (pre-split, MAIN) -----------
__global__ __launch_bounds__(256)
void k_csr_gemm1_ps(const int* __restrict__ buf, const int* __restrict__ gcur,
                    int* __restrict__ cnt_l, int* __restrict__ cnt_r,
                    int* __restrict__ csr_l, int* __restrict__ csr_r,
                    const _Float16* __restrict__ xh_l, const _Float16* __restrict__ xl_l,
                    const _Float16* __restrict__ xh_r, const _Float16* __restrict__ xl_r,
                    const __half* __restrict__ wi1l, const float* __restrict__ as1l,
                    const float* __restrict__ ad1l,
                    const __half* __restrict__ wi1r, const float* __restrict__ as1r,
                    const float* __restrict__ ad1r,
                    __half* __restrict__ h_l, __half* __restrict__ h_r,
                    float* __restrict__ ssrc_l, float* __restrict__ sdst_l,
                    float* __restrict__ ssrc_r, float* __restrict__ sdst_r) {
    __shared__ __align__(16) char smem[50176];
    int b = blockIdx.x;
    if (b < 2 * NB) {
        csr_body(b, buf, gcur, cnt_l, cnt_r, csr_l, csr_r, smem);
    } else {
        b -= 2 * NB;
        if (b < GB)
            gemm_ps_body(b, xh_l, xl_l, wi1l, as1l, ad1l,
                         h_l, ssrc_l, sdst_l, smem);
        else
            gemm_ps_body(b - GB, xh_r, xl_r, wi1r, as1r, ad1r,
                         h_r, ssrc_r, sdst_r, smem);
    }
}

// ---------------- fused: CSR build || layer-1 GEMMs (fp32 direct, FALLBACK) -----
__global__ __launch_bounds__(256)
void k_csr_gemm1(const int* __restrict__ buf, const int* __restrict__ gcur,
                 int* __restrict__ cnt_l, int* __restrict__ cnt_r,
                 int* __restrict__ csr_l, int* __restrict__ csr_r,
                 const float* __restrict__ x_l, const float* __restrict__ x_r,
                 const __half* __restrict__ wi1l, const float* __restrict__ as1l,
                 const float* __restrict__ ad1l,
                 const __half* __restrict__ wi1r, const float* __restrict__ as1r,
                 const float* __restrict__ ad1r,
                 __half* __restrict__ h_l, __half* __restrict__ h_r,
                 float* __restrict__ ssrc_l, float* __restrict__ sdst_l,
                 float* __restrict__ ssrc_r, float* __restrict__ sdst_r) {
    __shared__ __align__(16) char smem[50176];
    int b = blockIdx.x;
    if (b < 2 * NB) {
        csr_body(b, buf, gcur, cnt_l, cnt_r, csr_l, csr_r, smem);
    } else {
        b -= 2 * NB;
        if (b < GB)
            gemm_mfma_body<float, 128>(b, x_l, wi1l, as1l, ad1l,
                                       h_l, ssrc_l, sdst_l, smem);
        else
            gemm_mfma_body<float, 128>(b - GB, x_r, wi1r, as1r, ad1r,
                                       h_r, ssrc_r, sdst_r, smem);
    }
}

// ---------------- layer-2 GEMMs (fp16 input, no lo term for x) ------------------
__global__ __launch_bounds__(256)
void k_gemm2x(const __half* __restrict__ f_l, const __half* __restrict__ f_r,
              const __half* __restrict__ wi2l, const float* __restrict__ as2l,
              const float* __restrict__ ad2l,
              const __half* __restrict__ wi2r, const float* __restrict__ as2r,
              const float* __restrict__ ad2r,
              __half* __restrict__ h_l, __half* __restrict__ h_r,
              float* __restrict__ ssrc_l, float* __restrict__ sdst_l,
              float* __restrict__ ssrc_r, float* __restrict__ sdst_r) {
    __shared__ __align__(16) char smem[24576];
    int b = blockIdx.x;
    if (b < GB)
        gemm_mfma_body<__half, 64>(b, (const __half*)f_l, wi2l, as2l, ad2l,
                                   h_l, ssrc_l, sdst_l, smem);
    else
        gemm_mfma_body<__half, 64>(b - GB, (const __half*)f_r, wi2r, as2r, ad2r,
                                   h_r, ssrc_r, sdst_r, smem);
}

// ---------------- per-destination softmax aggregation (static shift m=0) --------
__device__ __forceinline__
void att_body(int n, const __half* __restrict__ h,
              const float* __restrict__ ssrc, const float* __restrict__ sdst,
              const int* __restrict__ cnt, const int* __restrict__ csr,
              const float* __restrict__ bias, __half* __restrict__ out) {
    const int g  = threadIdx.x & 31;
    const int hs = g >> 4;
    const int j  = g & 15;
    const int ch = g * 4;

    float sd = sdst[n * 2 + hs];
    float es = ssrc[n * 2 + hs] + sd;
    es = es > 0.f ? es : NEG_SLOPE * es;
    const float wself = __expf(es);
    float zl = 0.f;

    uint2 sv = *(const uint2*)&h[(size_t)n * 128 + ch];
    __half2 sh0 = *(__half2*)&sv.x, sh1 = *(__half2*)&sv.y;
    float2 p01 = __half22float2(sh0), p23 = __half22float2(sh1);
    float a0 = wself * p01.x, a1 = wself * p01.y;
    float a2 = wself * p23.x, a3 = wself * p23.y;

    int b = n * PAD;
    const int e = b + cnt[n];
    while (b < e) {
        int c = e - b; if (c > 16) c = 16;
        int idx = b + (j < c ? j : c - 1);
        int sj = csr[idx];
        float ev = ssrc[sj * 2 + hs] + sd;
        ev = ev > 0.f ? ev : NEG_SLOPE * ev;
        float w = (j < c) ? __expf(ev) : 0.f;
        zl += w;
        int jj = 0;
        for (; jj + 4 <= c; jj += 4) {
            int s0 = __shfl(sj, jj,     32);
            int s1 = __shfl(sj, jj + 1, 32);
            int s2 = __shfl(sj, jj + 2, 32);
            int s3 = __shfl(sj, jj + 3, 32);
            float w0 = __shfl(w, hs * 16 + jj,     32);
            float w1 = __shfl(w, hs * 16 + jj + 1, 32);
            float w2 = __shfl(w, hs * 16 + jj + 2, 32);
            float w3 = __shfl(w, hs * 16 + jj + 3, 32);
            uint2 u0 = *(const uint2*)&h[(size_t)(unsigned)(s0 * 128 + ch)];
            uint2 u1 = *(const uint2*)&h[(size_t)(unsigned)(s1 * 128 + ch)];
            uint2 u2 = *(const uint2*)&h[(size_t)(unsigned)(s2 * 128 + ch)];
            uint2 u3 = *(const uint2*)&h[(size_t)(unsigned)(s3 * 128 + ch)];
            float2 f0a = __half22float2(*(__half2*)&u0.x), f0b = __half22float2(*(__half2*)&u0.y);
            float2 f1a = __half22float2(*(__half2*)&u1.x), f1b = __half22float2(*(__half2*)&u1.y);
            float2 f2a = __half22float2(*(__half2*)&u2.x), f2b = __half22float2(*(__half2*)&u2.y);
            float2 f3a = __half22float2(*(__half2*)&u3.x), f3b = __half22float2(*(__half2*)&u3.y);
            a0 = fmaf(w0, f0a.x, a0); a1 = fmaf(w0, f0a.y, a1);
            a2 = fmaf(w0, f0b.x, a2); a3 = fmaf(w0, f0b.y, a3);
            a0 = fmaf(w1, f1a.x, a0); a1 = fmaf(w1, f1a.y, a1);
            a2 = fmaf(w1, f1b.x, a2); a3 = fmaf(w1, f1b.y, a3);
            a0 = fmaf(w2, f2a.x, a0); a1 = fmaf(w2, f2a.y, a1);
            a2 = fmaf(w2, f2b.x, a2); a3 = fmaf(w2, f2b.y, a3);
            a0 = fmaf(w3, f3a.x, a0); a1 = fmaf(w3, f3a.y, a1);
            a2 = fmaf(w3, f3b.x, a2); a3 = fmaf(w3, f3b.y, a3);
        }
        for (; jj < c; ++jj) {
            int s0   = __shfl(sj, jj, 32);
            float w0 = __shfl(w, hs * 16 + jj, 32);
            uint2 u0 = *(const uint2*)&h[(size_t)(unsigned)(s0 * 128 + ch)];
            float2 f0a = __half22float2(*(__half2*)&u0.x), f0b = __half22float2(*(__half2*)&u0.y);
            a0 = fmaf(w0, f0a.x, a0); a1 = fmaf(w0, f0a.y, a1);
            a2 = fmaf(w0, f0b.x, a2); a3 = fmaf(w0, f0b.y, a3);
        }
        b += c;
    }

    zl += __shfl_xor(zl, 1, 32);
    zl += __shfl_xor(zl, 2, 32);
    zl += __shfl_xor(zl, 4, 32);
    zl += __shfl_xor(zl, 8, 32);
    const float z = wself + zl;

    float zi = 1.f / z;
    a0 *= zi; a1 *= zi; a2 *= zi; a3 *= zi;
    a0 = 0.5f * (a0 + __shfl_xor(a0, 16));
    a1 = 0.5f * (a1 + __shfl_xor(a1, 16));
    a2 = 0.5f * (a2 + __shfl_xor(a2, 16));
    a3 = 0.5f * (a3 + __shfl_xor(a3, 16));
    if (hs == 0) {
        float4 bv = *(const float4*)&bias[ch];
        a0 += bv.x; a1 += bv.y; a2 += bv.z; a3 += bv.w;
        a0 = a0 > 0.f ? a0 : 0.f;
        a1 = a1 > 0.f ? a1 : 0.f;
        a2 = a2 > 0.f ? a2 : 0.f;
        a3 = a3 > 0.f ? a3 : 0.f;
        __align__(8) __half2 hp[2];
        hp[0] = __floats2half2_rn(a0, a1);
        hp[1] = __floats2half2_rn(a2, a3);
        *(uint2*)&out[(size_t)n * 64 + ch] = *(uint2*)hp;
    }
}

__global__ __launch_bounds__(256)
void k_att2x(const __half* __restrict__ h_l, const __half* __restrict__ h_r,
             const float* __restrict__ ssrc_l, const float* __restrict__ sdst_l,
             const float* __restrict__ ssrc_r, const float* __restrict__ sdst_r,
             const int* __restrict__ cnt_l, const int* __restrict__ csr_l,
             const int* __restrict__ cnt_r, const int* __restrict__ csr_r,
             const float* __restrict__ bias_l, const float* __restrict__ bias_r,
             __half* __restrict__ feat_l, __half* __restrict__ feat_r) {
    int blk = blockIdx.x;
    bool right = blk >= AB2;
    int n = (blk - (right ? AB2 : 0)) * 8 + (threadIdx.x >> 5);
    if (!right) att_body(n, h_l, ssrc_l, sdst_l, cnt_l, csr_l, bias_l, feat_l);
    else        att_body(n, h_r, ssrc_r, sdst_r, cnt_r, csr_r, bias_r, feat_r);
}

// ---------------- merge + FC1 + FC2 ----------------
__global__ __launch_bounds__(256)
void k_fc(const __half* __restrict__ fl, const __half* __restrict__ fr,
          const int* __restrict__ ll, const int* __restrict__ lr,
          const float* __restrict__ w1, const float* __restrict__ b1,
          const float* __restrict__ w2, const float* __restrict__ b2,
          float* __restrict__ out) {
    int b = blockIdx.x * 4 + (threadIdx.x >> 6);
    int j = threadIdx.x & 63;
    int la = ll[b], lb = lr[b];
    float v0 = __half2float(fl[(size_t)la * 64 + j]);
    float v1 = __half2float(fr[(size_t)lb * 64 + j]);
    float acc = b1[j];
    #pragma unroll 8
    for (int k = 0; k < 64; ++k)
        acc += __shfl(v0, k, 64) * w1[k * 64 + j];
    #pragma unroll 8
    for (int k = 0; k < 64; ++k)
        acc += __shfl(v1, k, 64) * w1[(64 + k) * 64 + j];
    float x1 = acc > 0.f ? acc : 0.f;
    float p0 = x1 * w2[j * 2 + 0];
    float p1 = x1 * w2[j * 2 + 1];
    #pragma unroll
    for (int o = 32; o >= 1; o >>= 1) {
        p0 += __shfl_xor(p0, o, 64);
        p1 += __shfl_xor(p1, o, 64);
    }
    if (j == 0) {
        out[b * 2 + 0] = p0 + b2[0];
        out[b * 2 + 1] = p1 + b2[1];
    }
}

extern "C" void kernel_launch(void* const* d_in, const int* in_sizes, int n_in,
                              void* d_out, int out_size, void* d_ws, size_t ws_size,
                              hipStream_t stream) {
    const float* x_l  = (const float*)d_in[0];
    const float* x_r  = (const float*)d_in[1];
    const int* ei_l  = (const int*)d_in[2];
    const int* ei_r  = (const int*)d_in[3];
    const int* lab_l = (const int*)d_in[4];
    const int* lab_r = (const int*)d_in[5];
    const float* w1l  = (const float*)d_in[6];
    const float* as1l = (const float*)d_in[7];
    const float* ad1l = (const float*)d_in[8];
    const float* b1l  = (const float*)d_in[9];
    const float* w2l  = (const float*)d_in[10];
    const float* as2l = (const float*)d_in[11];
    const float* ad2l = (const float*)d_in[12];
    const float* b2l  = (const float*)d_in[13];
    const float* w1r  = (const float*)d_in[14];
    const float* as1r = (const float*)d_in[15];
    const float* ad1r = (const float*)d_in[16];
    const float* b1r  = (const float*)d_in[17];
    const float* w2r  = (const float*)d_in[18];
    const float* as2r = (const float*)d_in[19];
    const float* ad2r = (const float*)d_in[20];
    const float* b2r  = (const float*)d_in[21];
    const float* fc1w = (const float*)d_in[22];
    const float* fc1b = (const float*)d_in[23];
    const float* fc2w = (const float*)d_in[24];
    const float* fc2b = (const float*)d_in[25];

    char* p = (char*)d_ws;
    auto alloc = [&](size_t bytes) -> void* {
        void* q = (void*)p;
        p += (bytes + 255) & ~(size_t)255;
        return q;
    };

    // ---- round-15 base carve (~119.4 MB) ----
    __half* h_l    = (__half*)alloc((size_t)NN * 128 * 2);
    __half* h_r    = (__half*)alloc((size_t)NN * 128 * 2);
    __half* feat_l = (__half*)alloc((size_t)NN * 64 * 2);
    __half* feat_r = (__half*)alloc((size_t)NN * 64 * 2);
    float* ssrc_l = (float*)alloc((size_t)NN * 2 * 4);
    float* sdst_l = (float*)alloc((size_t)NN * 2 * 4);
    float* ssrc_r = (float*)alloc((size_t)NN * 2 * 4);
    float* sdst_r = (float*)alloc((size_t)NN * 2 * 4);
    int* cnt2  = (int*)alloc(((size_t)2 * NN + 2 * NB) * 4);
    int* csr_l = (int*)alloc((size_t)NN * PAD * 4);
    int* csr_r = (int*)alloc((size_t)NN * PAD * 4);
    __half* wi1l = (__half*)alloc(65536);
    __half* wi1r = (__half*)alloc(65536);
    __half* wi2l = (__half*)alloc(32768);
    __half* wi2r = (__half*)alloc(32768);
    int* cnt_l = cnt2;
    int* cnt_r = cnt2 + NN;
    int* gcur  = cnt2 + 2 * NN;
    int* buf = (int*)feat_l;   // 16 MB bucket buffer overlays feat (dead till att1)

    // ---- extension: pre-split x arrays (+102.4 MB). Main path iff they fit. ----
    _Float16* xh_l = (_Float16*)alloc((size_t)NN * 128 * 2);
    _Float16* xl_l = (_Float16*)alloc((size_t)NN * 128 * 2);
    _Float16* xh_r = (_Float16*)alloc((size_t)NN * 128 * 2);
    _Float16* xl_r = (_Float16*)alloc((size_t)NN * 128 * 2);
    const bool mainpath = (size_t)(p - (char*)d_ws) <= ws_size;

    hipMemsetAsync(gcur, 0, (size_t)2 * NB * 4, stream);

    if (mainpath) {
        // K1: bucket sort || W-image prep || x hi/lo split
        k_bucket<<<2 * NCH + 12 + XSB, 256, 0, stream>>>(
            ei_l, ei_r, buf, gcur, w1l, w1r, w2l, w2r,
            wi1l, wi1r, wi2l, wi2r,
            x_l, x_r, xh_l, xl_l, xh_r, xl_r);

        // K2: CSR build || layer-1 GEMMs (pure-copy staging)
        k_csr_gemm1_ps<<<2 * NB + 2 * GB, 256, 0, stream>>>(
            buf, gcur, cnt_l, cnt_r, csr_l, csr_r,
            xh_l, xl_l, xh_r, xl_r,
            wi1l, as1l, ad1l, wi1r, as1r, ad1r,
            h_l, h_r, ssrc_l, sdst_l, ssrc_r, sdst_r);
    } else {
        // fallback: round-15 exact
        k_bucket<<<2 * NCH + 12, 256, 0, stream>>>(
            ei_l, ei_r, buf, gcur, w1l, w1r, w2l, w2r,
            wi1l, wi1r, wi2l, wi2r,
            x_l, x_r, nullptr, nullptr, nullptr, nullptr);

        k_csr_gemm1<<<2 * NB + 2 * GB, 256, 0, stream>>>(
            buf, gcur, cnt_l, cnt_r, csr_l, csr_r,
            x_l, x_r, wi1l, as1l, ad1l, wi1r, as1r, ad1r,
            h_l, h_r, ssrc_l, sdst_l, ssrc_r, sdst_r);
    }

    // K3: layer-1 attention
    k_att2x<<<2 * AB2, 256, 0, stream>>>(h_l, h_r, ssrc_l, sdst_l, ssrc_r, sdst_r,
                                         cnt_l, csr_l, cnt_r, csr_r,
                                         b1l, b1r, feat_l, feat_r);

    // K4: layer-2 GEMMs
    k_gemm2x<<<2 * GB, 256, 0, stream>>>(feat_l, feat_r,
                                         wi2l, as2l, ad2l, wi2r, as2r, ad2r,
                                         h_l, h_r, ssrc_l, sdst_l, ssrc_r, sdst_r);

    // K5: layer-2 attention
    k_att2x<<<2 * AB2, 256, 0, stream>>>(h_l, h_r, ssrc_l, sdst_l, ssrc_r, sdst_r,
                                         cnt_l, csr_l, cnt_r, csr_r,
                                         b2l, b2r, feat_l, feat_r);

    // K6: merge + MLP
    k_fc<<<(BB + 3) / 4, 256, 0, stream>>>(feat_l, feat_r, lab_l, lab_r,
                                           fc1w, fc1b, fc2w, fc2b,
                                           (float*)d_out);
}